// Round 2
// baseline (683.531 us; speedup 1.0000x reference)
//
#include <hip/hip_runtime.h>
#include <stdint.h>
#include <math.h>

#define B_ 4
#define S_ 2048
#define D_ 4096
#define O_ 4096
#define E_ 8
#define R_ 32
#define SCALING 2.0f
#define NOISE_EPS 0.01f

typedef unsigned short u16;

__device__ __forceinline__ float b2f(u16 u) {
  union { unsigned int i; float f; } v; v.i = ((unsigned int)u) << 16; return v.f;
}
__device__ __forceinline__ u16 f2b(float f) {
  union { unsigned int i; float f; } v; v.f = f;
  unsigned int i = v.i;
  return (u16)((i + 0x7FFFu + ((i >> 16) & 1u)) >> 16);  // RNE
}

// dtype-adaptive element access: bf=1 -> bf16, bf=0 -> fp32
__device__ __forceinline__ float ld(const void* p, size_t i, int bf) {
  return bf ? b2f(((const u16*)p)[i]) : ((const float*)p)[i];
}
__device__ __forceinline__ void st(void* p, size_t i, float v, int bf) {
  if (bf) ((u16*)p)[i] = f2b(v); else ((float*)p)[i] = v;
}

// ---------------------------------------------------------------------------
// Kernel 0: detect dtype of float inputs by inspecting x's bit patterns.
// For bf16 data, bits 14..7 of each 32b word are an exponent field (~[90,140]
// for N(0,1) values). For fp32 data they are random mantissa bits (~20% hit).
// ---------------------------------------------------------------------------
__global__ void k_detect(const unsigned int* __restrict__ xw, int* __restrict__ flag) {
  __shared__ int cnt;
  if (threadIdx.x == 0) cnt = 0;
  __syncthreads();
  unsigned int w = xw[threadIdx.x];
  unsigned int e = (w >> 7) & 0xFFu;
  if (e >= 90u && e <= 140u) atomicAdd(&cnt, 1);
  __syncthreads();
  if (threadIdx.x == 0) *flag = (cnt > 48) ? 1 : 0;
}

// ---------------------------------------------------------------------------
// Kernel 1: clean/noise logits. One block per (b,e).
// ---------------------------------------------------------------------------
__global__ __launch_bounds__(256) void k_logits(
    const void* __restrict__ x, const int* __restrict__ eof,
    const void* __restrict__ route_w, const void* __restrict__ noise_w,
    const int* __restrict__ flag, float* __restrict__ wsf) {
  int bf = *flag;
  int be = blockIdx.x;            // 0..31
  int b = be >> 3, e = be & 7;
  size_t xoff = ((size_t)b * S_ + (size_t)eof[b]) * D_;
  size_t woff = (size_t)e * D_;
  float ac = 0.f, an = 0.f;
  for (int d = threadIdx.x; d < D_; d += 256) {
    float xv = ld(x, xoff + d, bf);
    ac += xv * ld(route_w, woff + d, bf);
    an += xv * ld(noise_w, woff + d, bf);
  }
  __shared__ float rc[256], rn[256];
  rc[threadIdx.x] = ac; rn[threadIdx.x] = an;
  __syncthreads();
  for (int s = 128; s > 0; s >>= 1) {
    if (threadIdx.x < (unsigned)s) {
      rc[threadIdx.x] += rc[threadIdx.x + s];
      rn[threadIdx.x] += rn[threadIdx.x + s];
    }
    __syncthreads();
  }
  if (threadIdx.x == 0) { wsf[16 + be] = rc[0]; wsf[48 + be] = rn[0]; }
}

// ---------------------------------------------------------------------------
// Kernel 2: noisy top-2 softmax gates.
// ---------------------------------------------------------------------------
__global__ void k_gates(const void* __restrict__ noise, const int* __restrict__ flag,
                        float* __restrict__ wsf) {
  int bf = *flag;
  int b = threadIdx.x;
  if (b >= B_) return;
  float lg[E_];
  for (int e = 0; e < E_; e++) {
    float c = wsf[16 + b * 8 + e];
    float n = wsf[48 + b * 8 + e];
    float sp = (n > 20.f) ? n : log1pf(expf(n));   // softplus
    lg[e] = c + ld(noise, b * 8 + e, bf) * (sp + NOISE_EPS);
  }
  int i1 = 0; float v1 = lg[0];
  for (int e = 1; e < E_; e++) if (lg[e] > v1) { v1 = lg[e]; i1 = e; }
  int i2 = -1; float v2 = -3.0e38f;
  for (int e = 0; e < E_; e++) if (e != i1 && lg[e] > v2) { v2 = lg[e]; i2 = e; }
  float t = expf(v2 - v1);              // v2 <= v1, stable
  float g1 = 1.f / (1.f + t);
  float g2 = t / (1.f + t);
  for (int e = 0; e < E_; e++) wsf[80 + b * 8 + e] = 0.f;
  wsf[80 + b * 8 + i1] = g1;
  wsf[80 + b * 8 + i2] = g2;
}

// ---------------------------------------------------------------------------
// Kernel 3: Wc[b,o,r] = SCALING * sum_e gates[b,e] * B_w[e,o,r]   (fp32 out)
// ---------------------------------------------------------------------------
__global__ __launch_bounds__(256) void k_wc(
    const void* __restrict__ Bw, const int* __restrict__ flag,
    const float* __restrict__ gates, float* __restrict__ Wc) {
  int bf = *flag;
  int idx = blockIdx.x * 256 + threadIdx.x;     // 0 .. 524287
  int b = idx >> 17;
  int rem = idx & 131071;                       // o*32 + r
  float acc = 0.f;
#pragma unroll
  for (int e = 0; e < E_; e++) {
    acc += gates[b * 8 + e] * ld(Bw, (size_t)e * 131072 + rem, bf);
  }
  Wc[idx] = acc * SCALING;
}

// ---------------------------------------------------------------------------
// Kernel 4: shared[row, r] = sum_d x[row, d] * A_w[r, d]
// 256 threads, 16 rows/block, BK=256 fp32 LDS tiles.
// ---------------------------------------------------------------------------
#define BK 256
__global__ __launch_bounds__(256) void k_shared(
    const void* __restrict__ x, const void* __restrict__ Aw,
    const int* __restrict__ flag, float* __restrict__ sh_out) {
  __shared__ float xs[16][BK + 1];
  __shared__ float as[32][BK + 1];
  int bf = *flag;
  int tid = threadIdx.x;
  int row0 = blockIdx.x * 16;
  int rrow = tid >> 4;     // 0..15
  int rr = tid & 15;       // 0..15
  float acc0 = 0.f, acc1 = 0.f;
  for (int kc = 0; kc < D_; kc += BK) {
#pragma unroll
    for (int it = 0; it < 16; it++)
      xs[it][tid] = ld(x, (size_t)(row0 + it) * D_ + kc + tid, bf);
#pragma unroll
    for (int it = 0; it < 32; it++)
      as[it][tid] = ld(Aw, (size_t)it * D_ + kc + tid, bf);
    __syncthreads();
#pragma unroll 8
    for (int k = 0; k < BK; k++) {
      float xv = xs[rrow][k];
      acc0 += xv * as[rr][k];
      acc1 += xv * as[rr + 16][k];
    }
    __syncthreads();
  }
  sh_out[(size_t)(row0 + rrow) * R_ + rr] = acc0;
  sh_out[(size_t)(row0 + rrow) * R_ + rr + 16] = acc1;
}

// ---------------------------------------------------------------------------
// Kernel 5: out[row, o] = sum_r shared[row, r] * Wc[b, o, r]
// ---------------------------------------------------------------------------
__global__ __launch_bounds__(256) void k_out(
    const float* __restrict__ shw, const float* __restrict__ Wc,
    const int* __restrict__ flag, void* __restrict__ out) {
  __shared__ float sh[16][32];
  int bf = *flag;
  int tid = threadIdx.x;
  int row0 = blockIdx.x * 16;
  int b = row0 >> 11;
  ((float*)sh)[tid]       = shw[(size_t)row0 * R_ + tid];
  ((float*)sh)[tid + 256] = shw[(size_t)row0 * R_ + tid + 256];
  __syncthreads();
  const float* WcB = Wc + (size_t)b * (O_ * R_);
  for (int oc = 0; oc < 16; oc++) {
    int o = oc * 256 + tid;
    float w[32];
    const float4* wp = (const float4*)(WcB + (size_t)o * R_);
#pragma unroll
    for (int i = 0; i < 8; i++) {
      float4 f = wp[i];
      w[i * 4 + 0] = f.x; w[i * 4 + 1] = f.y; w[i * 4 + 2] = f.z; w[i * 4 + 3] = f.w;
    }
#pragma unroll
    for (int row = 0; row < 16; row++) {
      float acc = 0.f;
#pragma unroll
      for (int r = 0; r < R_; r++) acc += sh[row][r] * w[r];
      st(out, (size_t)(row0 + row) * O_ + o, acc, bf);
    }
  }
}

// ---------------------------------------------------------------------------
extern "C" void kernel_launch(void* const* d_in, const int* in_sizes, int n_in,
                              void* d_out, int out_size, void* d_ws, size_t ws_size,
                              hipStream_t stream) {
  const void* x       = d_in[0];                 // [4,2048,4096] f32 or bf16
  const int*  eof     = (const int*)d_in[1];     // [4]
  const void* noise   = d_in[2];                 // [4,8]
  const void* Aw      = d_in[3];                 // [32,4096]
  const void* Bw      = d_in[4];                 // [8,4096,32]
  const void* route_w = d_in[5];                 // [8,4096]
  const void* noise_w = d_in[6];                 // [8,4096]
  float* wsf = (float*)d_ws;
  int* flag = (int*)wsf;                         // wsf[0]
  // ws layout (floats): [0] flag | [16,48) clean | [48,80) noise logits |
  // [80,112) gates | [112, +524288) Wc | then 262144 floats of shared
  float* gates = wsf + 80;
  float* Wc    = wsf + 112;
  float* shw   = wsf + 112 + (size_t)B_ * O_ * R_;

  k_detect<<<1, 64, 0, stream>>>((const unsigned int*)x, flag);
  k_logits<<<B_ * E_, 256, 0, stream>>>(x, eof, route_w, noise_w, flag, wsf);
  k_gates<<<1, 64, 0, stream>>>(noise, flag, wsf);
  k_wc<<<(B_ * O_ * R_) / 256, 256, 0, stream>>>(Bw, flag, gates, Wc);
  k_shared<<<(B_ * S_) / 16, 256, 0, stream>>>(x, Aw, flag, shw);
  k_out<<<(B_ * S_) / 16, 256, 0, stream>>>(shw, Wc, flag, d_out);
}